// Round 14
// baseline (331.357 us; speedup 1.0000x reference)
//
#include <hip/hip_runtime.h>

typedef unsigned short u16;
typedef unsigned int u32;
typedef __attribute__((ext_vector_type(8))) short bf16x8;
typedef __attribute__((ext_vector_type(4))) float f32x4;

#define WD 160
#define HW 25600
#define NPIXF 204800.0f
#define BNEPS 1e-5f
#define SLOTB 6553600ll
#define BATB  13107200ll

__device__ __forceinline__ float bf2f(u16 u){ return __uint_as_float(((u32)u)<<16); }
__device__ __forceinline__ u16 f2bf(float f){ u32 x=__float_as_uint(f); return (u16)((x + 0x7FFFu + ((x>>16)&1u))>>16); }
__device__ __forceinline__ u32 pack2(float a,float b){ return (u32)f2bf(a) | ((u32)f2bf(b)<<16); }

__device__ __forceinline__ f32x4 MF(bf16x8 a, bf16x8 b, f32x4 c){
  return __builtin_amdgcn_mfma_f32_16x16x32_bf16(a, b, c, 0, 0, 0);
}
__device__ __forceinline__ void gload16(const void* g, void* l){
  __builtin_amdgcn_global_load_lds((const __attribute__((address_space(1))) void*)(g),
                                   (__attribute__((address_space(3))) void*)(l), 16, 0, 0);
}

// ============================================================================
// weight prep: wp1 [icb2][kc4][oc128][i8]  wp2 [icb4][tap9][kc4][oc64][i8]
// wp3/wp4 [icb2][tap9][oc64][k32]
// ============================================================================
__global__ __launch_bounds__(256) void k_prepw(
    const float* __restrict__ w1, const float* __restrict__ w2,
    const float* __restrict__ w3, const float* __restrict__ w4,
    u16* __restrict__ wp1, u16* __restrict__ wp2,
    u16* __restrict__ wp3, u16* __restrict__ wp4)
{
  int t = blockIdx.x*256 + threadIdx.x;
  if (t < 8192){
    int i = t&7, oc = (t>>3)&127, kc = (t>>10)&3, icb = t>>12;
    wp1[t] = f2bf(w1[oc*64 + icb*32 + kc*8 + i]);
  }
  int u = t - 8192;
  if (u >= 0 && u < 73728){
    int i = u&7, oc = (u>>3)&63, kc = (u>>9)&3, v = u>>11;
    int icb = (v*57)>>9; int tap = v - icb*9;
    wp2[u] = f2bf(w2[(oc*128 + icb*32 + kc*8 + i)*9 + tap]);
  }
  int u3 = t - (8192+73728);
  if (u3 >= 0 && u3 < 36864){
    int k = u3&31, oc = (u3>>5)&63, v = u3>>11;
    int icb = (v >= 9) ? 1 : 0; int tap = v - icb*9;
    wp3[u3] = f2bf(w3[(oc*64 + icb*32 + k)*9 + tap]);
    wp4[u3] = f2bf(w4[(oc*64 + icb*32 + k)*9 + tap]);
  }
}

// ============================================================================
// conv1 (verified): b128 conflict-free LDS staging from x f32.
// NEW: optionally mirrors staged bf16 chunks to xb16 (NHWC [b][px][64]) in ws
// — free producer for conv34-job1's gload16 staging.
// ============================================================================
__global__ __launch_bounds__(256,4) void k_conv1(
    const float* __restrict__ x, const u16* __restrict__ wp1,
    char* __restrict__ dout, float* __restrict__ stats, int nslot,
    u16* __restrict__ xb16o)
{
  __shared__ __align__(16) char Xs[16384];
  const int tid = threadIdx.x, lane = tid&63, w = tid>>6;
  const int l15 = lane&15, kc = lane>>4;
  int flat = blockIdx.x + 200*blockIdx.y;
  flat = (flat&7)*200 + (flat>>3);
  const int b = flat/200, bx = flat - b*200;
  const int px0 = bx*128;
  const float* xb = x + (size_t)b*64*HW;

#pragma unroll
  for (int q=0; q<4; ++q){
    int s = q*256 + tid;
    int px = s & 127, ck = (s>>7)&3, icb = s>>9;
    const float* pb = xb + (size_t)(icb*32 + ck*8)*HW + px0 + px;
    u32 w4[4];
#pragma unroll
    for (int j=0;j<4;++j)
      w4[j] = pack2(pb[(size_t)(2*j)*HW], pb[(size_t)(2*j+1)*HW]);
    uint4 v4 = make_uint4(w4[0],w4[1],w4[2],w4[3]);
    *(uint4*)(Xs + icb*8192 + px*64 + ((ck ^ ((px>>1)&3))<<4)) = v4;
    if (xb16o)
      *(uint4*)(xb16o + (size_t)b*HW*64 + (size_t)(px0+px)*64 + icb*32 + ck*8) = v4;
  }
  __syncthreads();

  f32x4 acc[4][4];
  for (int t=0;t<4;++t) for (int o=0;o<4;++o) acc[t][o] = (f32x4){0.f,0.f,0.f,0.f};
  const int och = (w>>1)*64;
  int a1off[4];
  for (int t=0;t<4;++t){
    int px = (w&1)*64 + t*16 + l15;
    a1off[t] = px*64 + ((kc ^ ((px>>1)&3))<<4);
  }
#pragma unroll
  for (int icb=0; icb<2; ++icb){
    bf16x8 a[4], bw[4];
#pragma unroll
    for (int t=0;t<4;++t) a[t] = *(const bf16x8*)(Xs + icb*8192 + a1off[t]);
#pragma unroll
    for (int o=0;o<4;++o)
      bw[o] = *(const bf16x8*)(wp1 + ((size_t)(icb*4 + kc)*128 + och + o*16 + l15)*8);
#pragma unroll
    for (int t=0;t<4;++t)
#pragma unroll
      for (int o=0;o<4;++o)
        acc[t][o] = MF(a[t], bw[o], acc[t][o]);
  }

  u16* c1 = (u16*)(dout + (size_t)b*BATB);
  float sa[4]={0,0,0,0}, sq[4]={0,0,0,0};
  for (int t=0;t<4;++t){
    int pxb = px0 + (w&1)*64 + t*16 + kc*4;
    for (int o=0;o<4;++o){
      int oc = och + o*16 + l15;
#pragma unroll
      for (int r=0;r<4;++r){
        float v = acc[t][o][r];
        c1[(size_t)(pxb + r)*128 + oc] = f2bf(v);
        sa[o]+=v; sq[o]+=v*v;
      }
    }
  }
  const int slot = flat & (nslot-1);
  for (int o=0;o<4;++o){
    float s1_=sa[o], s2_=sq[o];
    s1_+=__shfl_xor(s1_,16); s2_+=__shfl_xor(s2_,16);
    s1_+=__shfl_xor(s1_,32); s2_+=__shfl_xor(s2_,32);
    if (lane < 16){
      float* p = stats + ((size_t)slot*128 + och + o*16 + l15)*4;
      atomicAdd(p, s1_); atomicAdd(p+1, s2_);
    }
  }
}

// fold S2 (t<128) and S3 (t>=128) -> f23[256][2]
__global__ void k_fold23(const float* __restrict__ s2, const float* __restrict__ s3,
                         float* __restrict__ f23, int nslot){
  int t = threadIdx.x;
  const float* src = (t < 128) ? s2 : s3;
  int c = t & 127;
  float sm=0.f, sq=0.f;
  for (int s=0;s<nslot;++s){ const float* p = src + ((size_t)s*128 + c)*4; sm+=p[0]; sq+=p[1]; }
  f23[t*2] = sm; f23[t*2+1] = sq;
}

// ============================================================================
// conv2 (verified): BN1 affine+relu in register staging. raw2 -> odd-lo.
// ============================================================================
__global__ __launch_bounds__(256,4) void k_conv2(
    char* __restrict__ dout, const u16* __restrict__ wp2,
    const float* __restrict__ S0, const float* __restrict__ g1,
    const float* __restrict__ be1,
    float* __restrict__ statsO, int nslot)
{
  __shared__ __align__(16) char Xs[21760];
  __shared__ __align__(16) float scbi[128][2];
  const int tid = threadIdx.x, lane = tid&63, w = tid>>6;
  const int l15 = lane&15, kc = lane>>4;
  int flat = blockIdx.x + 5*(blockIdx.y + 20*blockIdx.z);
  flat = (flat&7)*100 + (flat>>3);
  const int b = flat/100; int r100 = flat - b*100;
  const int by = r100/5, bx = r100 - by*5;
  const int gx0 = bx*32, gy0 = by*8;
  const u16* c1raw = (const u16*)(dout + (size_t)b*BATB);
  u16* raw2 = (u16*)(dout + (size_t)b*BATB + SLOTB);

  if (tid < 128){
    float sm=0.f, sq=0.f;
    for (int s=0;s<nslot;++s){ const float* p = S0 + ((size_t)s*128 + tid)*4; sm+=p[0]; sq+=p[1]; }
    float m = sm/NPIXF;
    float v = sq/NPIXF - m*m;
    float sc = g1[tid]*rsqrtf(v + BNEPS);
    scbi[tid][0] = sc; scbi[tid][1] = be1[tid] - m*sc;
  }

  f32x4 acc[4][4];
  for (int t=0;t<4;++t) for (int o=0;o<4;++o) acc[t][o] = (f32x4){0.f,0.f,0.f,0.f};

  int xon[2][3];
  for (int h=0;h<2;++h) for (int dx=0;dx<3;++dx){
    int xi = l15 + h*16 + dx;
    xon[h][dx] = xi*64 + ((kc ^ ((xi>>1)&3))<<4);
  }

  __syncthreads();
  for (int icb=0; icb<4; ++icb){
    if (icb) __syncthreads();
    for (int s = tid; s < 1360; s += 256){
      int p = s>>2, sub = s&3;
      int yy = (int)(((u32)p*241u)>>13);
      int xi = p - yy*34;
      int gy = gy0 - 1 + yy, gx = gx0 - 1 + xi;
      int c = sub ^ ((xi>>1)&3);
      uint4 o4 = make_uint4(0,0,0,0);
      if ((unsigned)gy < 160u && (unsigned)gx < 160u){
        int cb = icb*32 + c*8;
        uint4 q = *(const uint4*)(c1raw + ((size_t)(gy*WD+gx)*128 + cb));
        u32 ww[4] = {q.x,q.y,q.z,q.w};
        u32 ro[4];
#pragma unroll
        for (int j=0;j<4;++j){
          float lo = bf2f((u16)(ww[j]&0xFFFFu)), hi = bf2f((u16)(ww[j]>>16));
          lo = fmaxf(0.f, lo*scbi[cb+2*j][0]   + scbi[cb+2*j][1]);
          hi = fmaxf(0.f, hi*scbi[cb+2*j+1][0] + scbi[cb+2*j+1][1]);
          ro[j] = pack2(lo, hi);
        }
        o4 = make_uint4(ro[0],ro[1],ro[2],ro[3]);
      }
      *(uint4*)(Xs + p*64 + sub*16) = o4;
    }
    __syncthreads();
#pragma unroll
    for (int tap=0; tap<9; ++tap){
      const int dy = tap/3, dx = tap - dy*3;
      bf16x8 a[4], bw[4];
#pragma unroll
      for (int o=0;o<4;++o)
        bw[o] = *(const bf16x8*)(wp2 + ((size_t)((icb*9 + tap)*4 + kc)*64 + o*16 + l15)*8);
#pragma unroll
      for (int t=0;t<4;++t)
        a[t] = *(const bf16x8*)(Xs + (2*w + (t>>1) + dy)*2176 + xon[t&1][dx]);
#pragma unroll
      for (int t=0;t<4;++t)
#pragma unroll
        for (int o=0;o<4;++o)
          acc[t][o] = MF(a[t], bw[o], acc[t][o]);
    }
  }

  float sa[4]={0,0,0,0}, sq[4]={0,0,0,0};
  for (int t=0;t<4;++t){
    int gy = gy0 + 2*w + (t>>1);
    int gxb = gx0 + (t&1)*16 + kc*4;
    for (int o=0;o<4;++o){
      int oc = o*16 + l15;
#pragma unroll
      for (int r=0;r<4;++r){
        float v = acc[t][o][r];
        raw2[(size_t)(gy*WD + gxb + r)*64 + oc] = f2bf(v);
        sa[o]+=v; sq[o]+=v*v;
      }
    }
  }
  int slot = flat & (nslot-1);
  for (int o=0;o<4;++o){
    float s1_=sa[o], s2_=sq[o];
    s1_+=__shfl_xor(s1_,16); s2_+=__shfl_xor(s2_,16);
    s1_+=__shfl_xor(s1_,32); s2_+=__shfl_xor(s2_,32);
    if (lane<16){
      float* p = statsO + ((size_t)slot*128 + o*16 + l15)*4;
      atomicAdd(p,s1_); atomicAdd(p+1,s2_);
    }
  }
}

// ============================================================================
// row-tiled sobel (bigWS, r13-verified): block=(y,b), coalesced gload16 stage.
// ============================================================================
__global__ __launch_bounds__(256,2) void k_sobelrow(
    char* __restrict__ dout, const float* __restrict__ S1,
    const float* __restrict__ g2, const float* __restrict__ be2,
    u16* __restrict__ edge_base, long ebstride,
    const u16* __restrict__ zeros, int nslot)
{
  __shared__ __align__(16) char Xs[65536];
  __shared__ float ascS[64], abiS[64];
  const int tid = threadIdx.x;
  const int y = blockIdx.x, b = blockIdx.y;

  if (tid < 64){
    float sm=0.f, sq=0.f;
    for (int s=0;s<nslot;++s){ const float* p = S1 + ((size_t)s*128 + tid)*4; sm+=p[0]; sq+=p[1]; }
    float m = sm/NPIXF, v = sq/NPIXF - m*m;
    float sc = g2[tid]*rsqrtf(v + BNEPS);
    ascS[tid] = sc; abiS[tid] = be2[tid] - m*sc;
  }

  const u16* raw2 = (const u16*)(dout + (size_t)b*BATB + SLOTB);
#pragma unroll
  for (int it=0; it<16; ++it){
    int s = it*256 + tid;
    int r = (s >= 2624) ? 2 : ((s >= 1312) ? 1 : 0);
    int sl = s - r*1312;
    int p = sl>>3, c8 = sl&7;
    int yy = y - 1 + r, gx = p - 2;
    const u16* src = zeros + ((tid&63)<<3);
    if (s < 3936 && (unsigned)yy < 160u && (unsigned)gx < 160u)
      src = raw2 + ((size_t)(yy*WD + gx)*64 + c8*8);
    gload16(src, Xs + (it*256 + (tid & ~63))*16);
  }
  asm volatile("s_waitcnt vmcnt(0)" ::: "memory");
  __syncthreads();

  u16* edge = edge_base + (size_t)b*ebstride;
#pragma unroll
  for (int i=0; i<5; ++i){
    int s = i*256 + tid;
    int px = s>>3, c8 = s&7;
    const int ch0 = c8*8;
    float av[8] = {0,0,0,0,0,0,0,0};
    auto TAP = [&](int dy, int dx, float wt){
      int yy = y+dy, xx = px+dx;
      if ((unsigned)yy>=160u || (unsigned)xx>=160u) return;
      uint4 q = *(const uint4*)(Xs + (((1+dy)*1312 + (xx+2)*8 + c8)<<4));
      u32 ww[4] = {q.x,q.y,q.z,q.w};
#pragma unroll
      for (int j=0;j<4;++j){
        float lo = bf2f((u16)(ww[j]&0xFFFFu)), hi = bf2f((u16)(ww[j]>>16));
        lo = fmaxf(0.f, lo*ascS[ch0+2*j]   + abiS[ch0+2*j]);
        hi = fmaxf(0.f, hi*ascS[ch0+2*j+1] + abiS[ch0+2*j+1]);
        av[2*j]   += wt*lo;
        av[2*j+1] += wt*hi;
      }
    };
    TAP(-1,-1,4.f); TAP(-1,0,4.f);
    TAP(0,-2,-2.f); TAP(0,-1,-8.f); TAP(0,1,8.f); TAP(0,2,2.f);
    TAP(1,0,-4.f);  TAP(1,1,-4.f);
    uint4 o;
    o.x = pack2(av[0],av[1]); o.y = pack2(av[2],av[3]);
    o.z = pack2(av[4],av[5]); o.w = pack2(av[6],av[7]);
    *(uint4*)(edge + ((size_t)(y*WD + px)*64 + c8*8)) = o;
  }
}

// ============================================================================
// sobel (standalone, smallWS fallback — verified): raw2(odd-lo) -> edge
// ============================================================================
__global__ __launch_bounds__(256) void k_sobel(
    char* __restrict__ dout, const float* __restrict__ S1,
    const float* __restrict__ g2, const float* __restrict__ be2,
    u16* __restrict__ edge_base, long ebstride, int nslot)
{
  __shared__ float ascS[8], abiS[8];
  int tid = threadIdx.x;
  int b = blockIdx.z, cb = blockIdx.y;
  if (tid < 64){
    int c = cb*8 + (tid&7);
    float sm=0.f, sq=0.f;
    for (int s = tid>>3; s < nslot; s += 8){
      const float* p = S1 + ((size_t)s*128 + c)*4;
      sm += p[0]; sq += p[1];
    }
    sm += __shfl_xor(sm, 8);  sq += __shfl_xor(sq, 8);
    sm += __shfl_xor(sm, 16); sq += __shfl_xor(sq, 16);
    sm += __shfl_xor(sm, 32); sq += __shfl_xor(sq, 32);
    if (tid < 8){
      float m = sm/NPIXF, v = sq/NPIXF - m*m;
      float sc = g2[c]*rsqrtf(v+BNEPS);
      ascS[tid] = sc; abiS[tid] = be2[c] - m*sc;
    }
  }
  __syncthreads();
  int px = blockIdx.x*256 + tid;
  int y = (int)(((u32)px*52429u)>>23);
  int x = px - y*WD;
  const u16* raw2 = (const u16*)(dout + (size_t)b*BATB + SLOTB);
  u16* edge = edge_base + (size_t)b*ebstride;
  float av[8] = {0,0,0,0,0,0,0,0};
  auto TAP = [&](int dy, int dx, float wt){
    int yy = y+dy, xx = x+dx;
    if ((unsigned)yy>=160u || (unsigned)xx>=160u) return;
    uint4 q = *(const uint4*)(raw2 + ((size_t)(yy*WD+xx)*64 + cb*8));
    u32 ww[4] = {q.x,q.y,q.z,q.w};
#pragma unroll
    for (int j=0;j<4;++j){
      float lo = bf2f((u16)(ww[j]&0xFFFFu)), hi = bf2f((u16)(ww[j]>>16));
      lo = fmaxf(0.f, lo*ascS[2*j]   + abiS[2*j]);
      hi = fmaxf(0.f, hi*ascS[2*j+1] + abiS[2*j+1]);
      av[2*j]   += wt*lo;
      av[2*j+1] += wt*hi;
    }
  };
  TAP(-1,-1,4.f); TAP(-1,0,4.f);
  TAP(0,-2,-2.f); TAP(0,-1,-8.f); TAP(0,1,8.f); TAP(0,2,2.f);
  TAP(1,0,-4.f);  TAP(1,1,-4.f);
  uint4 o;
  o.x = pack2(av[0],av[1]); o.y = pack2(av[2],av[3]);
  o.z = pack2(av[4],av[5]); o.w = pack2(av[6],av[7]);
  *(uint4*)(edge + ((size_t)px*64 + cb*8)) = o;
}

// ============================================================================
// conv3/conv4 (132us structure): 24.6KB per-icb phases, lb(256,2).
// job1 staging: gload16 from xb16 (if available) else float4-quad (verbatim).
// job0: edge gload16 + vmcnt(0). mode 2 merged; 0/1 split.
// ============================================================================
__global__ __launch_bounds__(256,2) void k_conv34(
    char* __restrict__ dout, const float* __restrict__ x,
    const u16* __restrict__ xb16,
    const u16* __restrict__ wp3, const u16* __restrict__ wp4,
    float* __restrict__ st3, float* __restrict__ st4,
    const u16* __restrict__ zeros, const u16* __restrict__ edge_base,
    long ebstride, int nslot, int mode)
{
  __shared__ __align__(16) char Xs[24576];
  const int tid = threadIdx.x, lane = tid&63, w = tid>>6;
  const int l15 = lane&15, kc = lane>>4;
  int b, job;
  if (mode == 2){ b = blockIdx.z>>1; job = blockIdx.z&1; }
  else          { b = blockIdx.z;    job = mode; }
  const int gx0 = blockIdx.x*32, gy0 = blockIdx.y*8;
  const u16* wp = job ? wp4 : wp3;
  float* statsO = job ? st4 : st3;
  float* out = job ? (float*)(dout + (size_t)b*BATB)
                   : (float*)(dout + (size_t)b*BATB + SLOTB);
  const float* xb = x + (size_t)b*64*HW;
  const u16* edge = edge_base + (size_t)b*ebstride;
  // gload16 source for this job (NHWC [px][64] bf16 in both cases)
  const u16* nsrc = job ? (xb16 ? xb16 + (size_t)b*HW*64 : nullptr) : edge;

  f32x4 acc[4][4];
  for (int m=0;m<4;++m) for (int t=0;t<4;++t) acc[m][t] = (f32x4){0.f,0.f,0.f,0.f};
  int xon[2][3];
  for (int h=0;h<2;++h) for (int dx=0;dx<3;++dx){
    int xi = l15 + h*16 + dx;
    xon[h][dx] = xi*64 + ((kc ^ ((xi>>1)&3))<<4);
  }

  for (int icb=0; icb<2; ++icb){
    if (icb) __syncthreads();
    if (job == 1 && !nsrc){
      // float4-quad transpose staging from x f32 (verbatim fallback)
      for (int s = tid; s < 1600; s += 256){
        int s10 = (int)(((u32)s*6554u)>>16);
        int q = s - s10*10;
        int cp = (int)(((u32)s10*6554u)>>16);
        int yq = s10 - cp*10;
        int gy = gy0 - 1 + yq;
        int gxq = gx0 - 4 + q*4;
        float fa[4] = {0,0,0,0}, fb[4] = {0,0,0,0};
        if ((unsigned)gy < 160u){
          const float* pa = xb + (size_t)(icb*32 + cp*2)*HW + gy*WD + gxq;
          if (gxq >= 0 && gxq + 3 < 160){
            float4 va = *(const float4*)pa;
            float4 vb = *(const float4*)(pa + HW);
            fa[0]=va.x; fa[1]=va.y; fa[2]=va.z; fa[3]=va.w;
            fb[0]=vb.x; fb[1]=vb.y; fb[2]=vb.z; fb[3]=vb.w;
          } else {
#pragma unroll
            for (int e=0;e<4;++e){
              int gx = gxq + e;
              if ((unsigned)gx < 160u){ fa[e] = pa[e]; fb[e] = pa[e + HW]; }
            }
          }
        }
#pragma unroll
        for (int e=0;e<4;++e){
          int xi = gxq + e - (gx0 - 1);
          if ((unsigned)xi < 34u){
            int phys = (yq*34 + xi)*64 + (((cp>>2) ^ ((xi>>1)&3))<<4) + (cp&3)*4;
            *(u32*)(Xs + phys) = pack2(fa[e], fb[e]);
          }
        }
      }
    } else {
      // gload16 staging from NHWC bf16 (edge or xb16)
      for (int it=0; it<6; ++it){
        int s = it*256 + tid;
        int p = s>>2, sub = s&3;
        int yy = (int)(((u32)p*241u)>>13);
        int xi = p - yy*34;
        int gy = gy0-1+yy, gx = gx0-1+xi;
        int c = sub ^ ((xi>>1)&3);
        const u16* src = zeros + ((tid&63)<<3);
        if (p<340 && (unsigned)gy<160u && (unsigned)gx<160u)
          src = nsrc + ((size_t)(gy*WD+gx)*64 + icb*32 + c*8);
        gload16(src, Xs + (it*256 + (tid & ~63))*16);
      }
      asm volatile("s_waitcnt vmcnt(0)" ::: "memory");
    }
    __syncthreads();

#pragma unroll
    for (int tap=0; tap<9; ++tap){
      const int dy = tap/3, dx = tap - dy*3;
      bf16x8 a[4], bv[4];
#pragma unroll
      for (int m=0;m<4;++m)
        a[m] = *(const bf16x8*)(wp + ((size_t)((icb*9+tap)*64 + m*16 + l15)*32 + kc*8));
#pragma unroll
      for (int t=0;t<4;++t)
        bv[t] = *(const bf16x8*)(Xs + (2*w + (t>>1) + dy)*2176 + xon[t&1][dx]);
#pragma unroll
      for (int m=0;m<4;++m)
#pragma unroll
        for (int t=0;t<4;++t)
          acc[m][t] = MF(a[m], bv[t], acc[m][t]);
    }
  }

  float sa[4][4], sq[4][4];
  for (int m=0;m<4;++m) for (int r=0;r<4;++r){ sa[m][r]=0.f; sq[m][r]=0.f; }
  for (int m=0;m<4;++m){
    for (int t=0;t<4;++t){
      int gy = gy0 + 2*w + (t>>1);
      int gx = gx0 + (t&1)*16 + l15;
#pragma unroll
      for (int r=0;r<4;++r){
        float v = acc[m][t][r];
        out[(size_t)(m*16 + kc*4 + r)*HW + gy*WD + gx] = v;
        sa[m][r]+=v; sq[m][r]+=v*v;
      }
    }
  }
  int slot = (blockIdx.x + 5*(blockIdx.y + 20*blockIdx.z)) & (nslot-1);
  for (int m=0;m<4;++m)
    for (int r=0;r<4;++r){
      float s1_=sa[m][r], s2_=sq[m][r];
      s1_+=__shfl_xor(s1_,1); s2_+=__shfl_xor(s2_,1);
      s1_+=__shfl_xor(s1_,2); s2_+=__shfl_xor(s2_,2);
      s1_+=__shfl_xor(s1_,4); s2_+=__shfl_xor(s2_,4);
      s1_+=__shfl_xor(s1_,8); s2_+=__shfl_xor(s2_,8);
      if (l15==0){
        float* p = statsO + ((size_t)slot*128 + m*16 + kc*4 + r)*4;
        atomicAdd(p,s1_); atomicAdd(p+1,s2_);
      }
    }
}

// final in-place BN+ReLU on d_out NCHW f32.
__global__ __launch_bounds__(256) void k_bnrelu(
    float* __restrict__ io, const float* __restrict__ f23,
    const float* __restrict__ g3, const float* __restrict__ be3,
    const float* __restrict__ g4, const float* __restrict__ be4)
{
  size_t e = ((size_t)blockIdx.x*256 + threadIdx.x)*8;
  int cg = (int)((e/HW) & 127);
  float* p = io + (size_t)blockIdx.y*3276800 + e;
  float sm,sq,gg,bb;
  if (cg>=64){ int c=cg-64; sm=f23[c*2]; sq=f23[c*2+1]; gg=g3[c]; bb=be3[c]; }
  else       { sm=f23[(128+cg)*2]; sq=f23[(128+cg)*2+1]; gg=g4[cg]; bb=be4[cg]; }
  float m = sm/NPIXF;
  float v = sq/NPIXF - m*m;
  float sc = gg*rsqrtf(v + BNEPS);
  float bi = bb - m*sc;
  float4 a = *(float4*)p;
  float4 bq = *(float4*)(p+4);
  a.x=fmaxf(0.f,a.x*sc+bi); a.y=fmaxf(0.f,a.y*sc+bi);
  a.z=fmaxf(0.f,a.z*sc+bi); a.w=fmaxf(0.f,a.w*sc+bi);
  bq.x=fmaxf(0.f,bq.x*sc+bi); bq.y=fmaxf(0.f,bq.y*sc+bi);
  bq.z=fmaxf(0.f,bq.z*sc+bi); bq.w=fmaxf(0.f,bq.w*sc+bi);
  *(float4*)p = a;
  *(float4*)(p+4) = bq;
}

extern "C" void kernel_launch(void* const* d_in, const int* in_sizes, int n_in,
                              void* d_out, int out_size, void* d_ws, size_t ws_size,
                              hipStream_t stream)
{
  const float* x   = (const float*)d_in[0];
  const float* w1  = (const float*)d_in[1];
  const float* g1  = (const float*)d_in[3];
  const float* be1 = (const float*)d_in[4];
  const float* w2  = (const float*)d_in[5];
  const float* g2  = (const float*)d_in[7];
  const float* be2 = (const float*)d_in[8];
  const float* w3  = (const float*)d_in[9];
  const float* g3  = (const float*)d_in[11];
  const float* be3 = (const float*)d_in[12];
  const float* w4  = (const float*)d_in[13];
  const float* g4  = (const float*)d_in[15];
  const float* be4 = (const float*)d_in[16];
  (void)in_sizes; (void)n_in; (void)out_size;
  // biases b1..b4 dropped — training-mode BN is shift-invariant.

  int nslot = 32;
  auto need = [&](int ns)->size_t{
    return (size_t)4*ns*128*4*4 + 4096 + (size_t)(8192+73728+36864+36864)*2 + 1024;
  };
  while (nslot > 1 && need(nslot) > ws_size) nslot >>= 1;
  if (need(nslot) > ws_size) return;

  char* ws = (char*)d_ws;
  float* S = (float*)ws;
  size_t stg = (size_t)nslot*128*4;
  float* S0=S, *S1=S+stg, *S2=S+2*stg, *S3=S+3*stg;
  float* F = S + 4*stg;
  u16* wp1 = (u16*)(F + 1024);
  u16* wp2 = wp1 + 8192;
  u16* wp3 = wp2 + 73728;
  u16* wp4 = wp3 + 36864;
  u16* zeros = wp4 + 36864;
  size_t base = need(nslot);
  bool bigB = (ws_size >= base + 26214400ull);          // edge in ws
  bool bigA = (ws_size >= base + 2*26214400ull);        // + xb16 in ws
  u16* edge_base; long ebstride;
  if (bigB){ edge_base = (u16*)(ws + base); ebstride = 64L*HW; }
  else     { edge_base = (u16*)((char*)d_out + 3276800); ebstride = BATB/2; }
  u16* xb16 = bigA ? (u16*)(ws + base + 26214400) : nullptr;

  hipMemsetAsync(S, 0, 4*stg*sizeof(float), stream);
  hipMemsetAsync(zeros, 0, 1024, stream);

  k_prepw<<<464, 256, 0, stream>>>(w1, w2, w3, w4, wp1, wp2, wp3, wp4);
  k_conv1<<<dim3(200,8), 256, 0, stream>>>(x, wp1, (char*)d_out, S0, nslot, xb16);
  k_conv2<<<dim3(5,20,8), 256, 0, stream>>>((char*)d_out, wp2, S0, g1, be1, S1, nslot);
  if (bigB){
    k_sobelrow<<<dim3(160,8), 256, 0, stream>>>((char*)d_out, S1, g2, be2,
                                                edge_base, ebstride, zeros, nslot);
    k_conv34<<<dim3(5,20,16), 256, 0, stream>>>((char*)d_out, x, xb16, wp3, wp4, S2, S3,
                                                zeros, edge_base, ebstride, nslot, 2);
  } else {
    k_sobel<<<dim3(100,8,8), 256, 0, stream>>>((char*)d_out, S1, g2, be2,
                                               edge_base, ebstride, nslot);
    k_conv34<<<dim3(5,20,8), 256, 0, stream>>>((char*)d_out, x, nullptr, wp3, wp4, S2, S3,
                                               zeros, edge_base, ebstride, nslot, 0);
    k_conv34<<<dim3(5,20,8), 256, 0, stream>>>((char*)d_out, x, nullptr, wp3, wp4, S2, S3,
                                               zeros, edge_base, ebstride, nslot, 1);
  }
  k_fold23<<<1, 256, 0, stream>>>(S2, S3, F, nslot);
  k_bnrelu<<<dim3(1600,8), 256, 0, stream>>>((float*)d_out, F, g3, be3, g4, be4);
}

// Round 16
// 321.300 us; speedup vs baseline: 1.0313x; 1.0313x over previous
//
#include <hip/hip_runtime.h>

typedef unsigned short u16;
typedef unsigned int u32;
typedef __attribute__((ext_vector_type(8))) short bf16x8;
typedef __attribute__((ext_vector_type(4))) float f32x4;
typedef __attribute__((ext_vector_type(4))) unsigned int u32x4;

#define WD 160
#define HW 25600
#define NPIXF 204800.0f
#define BNEPS 1e-5f
#define SLOTB 6553600ll
#define BATB  13107200ll

__device__ __forceinline__ float bf2f(u16 u){ return __uint_as_float(((u32)u)<<16); }
__device__ __forceinline__ u16 f2bf(float f){ u32 x=__float_as_uint(f); return (u16)((x + 0x7FFFu + ((x>>16)&1u))>>16); }
__device__ __forceinline__ u32 pack2(float a,float b){ return (u32)f2bf(a) | ((u32)f2bf(b)<<16); }

__device__ __forceinline__ f32x4 MF(bf16x8 a, bf16x8 b, f32x4 c){
  return __builtin_amdgcn_mfma_f32_16x16x32_bf16(a, b, c, 0, 0, 0);
}
__device__ __forceinline__ void gload16(const void* g, void* l){
  __builtin_amdgcn_global_load_lds((const __attribute__((address_space(1))) void*)(g),
                                   (__attribute__((address_space(3))) void*)(l), 16, 0, 0);
}

// ============================================================================
// weight prep: wp1 [icb2][kc4][oc128][i8]  wp2 [icb4][tap9][kc4][oc64][i8]
// wp3/wp4 [icb2][tap9][oc64][k32]
// ============================================================================
__global__ __launch_bounds__(256) void k_prepw(
    const float* __restrict__ w1, const float* __restrict__ w2,
    const float* __restrict__ w3, const float* __restrict__ w4,
    u16* __restrict__ wp1, u16* __restrict__ wp2,
    u16* __restrict__ wp3, u16* __restrict__ wp4)
{
  int t = blockIdx.x*256 + threadIdx.x;
  if (t < 8192){
    int i = t&7, oc = (t>>3)&127, kc = (t>>10)&3, icb = t>>12;
    wp1[t] = f2bf(w1[oc*64 + icb*32 + kc*8 + i]);
  }
  int u = t - 8192;
  if (u >= 0 && u < 73728){
    int i = u&7, oc = (u>>3)&63, kc = (u>>9)&3, v = u>>11;
    int icb = (v*57)>>9; int tap = v - icb*9;
    wp2[u] = f2bf(w2[(oc*128 + icb*32 + kc*8 + i)*9 + tap]);
  }
  int u3 = t - (8192+73728);
  if (u3 >= 0 && u3 < 36864){
    int k = u3&31, oc = (u3>>5)&63, v = u3>>11;
    int icb = (v >= 9) ? 1 : 0; int tap = v - icb*9;
    wp3[u3] = f2bf(w3[(oc*64 + icb*32 + k)*9 + tap]);
    wp4[u3] = f2bf(w4[(oc*64 + icb*32 + k)*9 + tap]);
  }
}

// ============================================================================
// conv1 (verified): b128 conflict-free LDS staging from x f32.
// xb16 mirror COALESCED from LDS post-sync (lane-consecutive 16B) with
// nontemporal stores (xb16 only consumed by conv34 -> keep out of L2).
// ============================================================================
__global__ __launch_bounds__(256,4) void k_conv1(
    const float* __restrict__ x, const u16* __restrict__ wp1,
    char* __restrict__ dout, float* __restrict__ stats, int nslot,
    u16* __restrict__ xb16o)
{
  __shared__ __align__(16) char Xs[16384];
  const int tid = threadIdx.x, lane = tid&63, w = tid>>6;
  const int l15 = lane&15, kc = lane>>4;
  int flat = blockIdx.x + 200*blockIdx.y;
  flat = (flat&7)*200 + (flat>>3);
  const int b = flat/200, bx = flat - b*200;
  const int px0 = bx*128;
  const float* xb = x + (size_t)b*64*HW;

#pragma unroll
  for (int q=0; q<4; ++q){
    int s = q*256 + tid;
    int px = s & 127, ck = (s>>7)&3, icb = s>>9;
    const float* pb = xb + (size_t)(icb*32 + ck*8)*HW + px0 + px;
    u32 w4[4];
#pragma unroll
    for (int j=0;j<4;++j)
      w4[j] = pack2(pb[(size_t)(2*j)*HW], pb[(size_t)(2*j+1)*HW]);
    *(uint4*)(Xs + icb*8192 + px*64 + ((ck ^ ((px>>1)&3))<<4))
        = make_uint4(w4[0],w4[1],w4[2],w4[3]);
  }
  __syncthreads();

  if (xb16o){
    u16* ob = xb16o + (size_t)b*HW*64 + (size_t)px0*64;
#pragma unroll
    for (int q=0; q<4; ++q){
      int s = q*256 + tid;               // out chunk s -> consecutive 16B
      int px = s>>3, c = s&7;
      int icb = c>>2, ck = c&3;
      u32x4 v = *(const u32x4*)(Xs + icb*8192 + px*64 + ((ck ^ ((px>>1)&3))<<4));
      __builtin_nontemporal_store(v, (u32x4*)(ob + (size_t)s*8));
    }
  }

  f32x4 acc[4][4];
  for (int t=0;t<4;++t) for (int o=0;o<4;++o) acc[t][o] = (f32x4){0.f,0.f,0.f,0.f};
  const int och = (w>>1)*64;
  int a1off[4];
  for (int t=0;t<4;++t){
    int px = (w&1)*64 + t*16 + l15;
    a1off[t] = px*64 + ((kc ^ ((px>>1)&3))<<4);
  }
#pragma unroll
  for (int icb=0; icb<2; ++icb){
    bf16x8 a[4], bw[4];
#pragma unroll
    for (int t=0;t<4;++t) a[t] = *(const bf16x8*)(Xs + icb*8192 + a1off[t]);
#pragma unroll
    for (int o=0;o<4;++o)
      bw[o] = *(const bf16x8*)(wp1 + ((size_t)(icb*4 + kc)*128 + och + o*16 + l15)*8);
#pragma unroll
    for (int t=0;t<4;++t)
#pragma unroll
      for (int o=0;o<4;++o)
        acc[t][o] = MF(a[t], bw[o], acc[t][o]);
  }

  u16* c1 = (u16*)(dout + (size_t)b*BATB);
  float sa[4]={0,0,0,0}, sq[4]={0,0,0,0};
  for (int t=0;t<4;++t){
    int pxb = px0 + (w&1)*64 + t*16 + kc*4;
    for (int o=0;o<4;++o){
      int oc = och + o*16 + l15;
#pragma unroll
      for (int r=0;r<4;++r){
        float v = acc[t][o][r];
        c1[(size_t)(pxb + r)*128 + oc] = f2bf(v);
        sa[o]+=v; sq[o]+=v*v;
      }
    }
  }
  const int slot = flat & (nslot-1);
  for (int o=0;o<4;++o){
    float s1_=sa[o], s2_=sq[o];
    s1_+=__shfl_xor(s1_,16); s2_+=__shfl_xor(s2_,16);
    s1_+=__shfl_xor(s1_,32); s2_+=__shfl_xor(s2_,32);
    if (lane < 16){
      float* p = stats + ((size_t)slot*128 + och + o*16 + l15)*4;
      atomicAdd(p, s1_); atomicAdd(p+1, s2_);
    }
  }
}

// fold S2 (t<128) and S3 (t>=128) -> f23[256][2]
__global__ void k_fold23(const float* __restrict__ s2, const float* __restrict__ s3,
                         float* __restrict__ f23, int nslot){
  int t = threadIdx.x;
  const float* src = (t < 128) ? s2 : s3;
  int c = t & 127;
  float sm=0.f, sq=0.f;
  for (int s=0;s<nslot;++s){ const float* p = src + ((size_t)s*128 + c)*4; sm+=p[0]; sq+=p[1]; }
  f23[t*2] = sm; f23[t*2+1] = sq;
}

// ============================================================================
// conv2 (verified): BN1 affine+relu in register staging. raw2 -> odd-lo.
// ============================================================================
__global__ __launch_bounds__(256,4) void k_conv2(
    char* __restrict__ dout, const u16* __restrict__ wp2,
    const float* __restrict__ S0, const float* __restrict__ g1,
    const float* __restrict__ be1,
    float* __restrict__ statsO, int nslot)
{
  __shared__ __align__(16) char Xs[21760];
  __shared__ __align__(16) float scbi[128][2];
  const int tid = threadIdx.x, lane = tid&63, w = tid>>6;
  const int l15 = lane&15, kc = lane>>4;
  int flat = blockIdx.x + 5*(blockIdx.y + 20*blockIdx.z);
  flat = (flat&7)*100 + (flat>>3);
  const int b = flat/100; int r100 = flat - b*100;
  const int by = r100/5, bx = r100 - by*5;
  const int gx0 = bx*32, gy0 = by*8;
  const u16* c1raw = (const u16*)(dout + (size_t)b*BATB);
  u16* raw2 = (u16*)(dout + (size_t)b*BATB + SLOTB);

  if (tid < 128){
    float sm=0.f, sq=0.f;
    for (int s=0;s<nslot;++s){ const float* p = S0 + ((size_t)s*128 + tid)*4; sm+=p[0]; sq+=p[1]; }
    float m = sm/NPIXF;
    float v = sq/NPIXF - m*m;
    float sc = g1[tid]*rsqrtf(v + BNEPS);
    scbi[tid][0] = sc; scbi[tid][1] = be1[tid] - m*sc;
  }

  f32x4 acc[4][4];
  for (int t=0;t<4;++t) for (int o=0;o<4;++o) acc[t][o] = (f32x4){0.f,0.f,0.f,0.f};

  int xon[2][3];
  for (int h=0;h<2;++h) for (int dx=0;dx<3;++dx){
    int xi = l15 + h*16 + dx;
    xon[h][dx] = xi*64 + ((kc ^ ((xi>>1)&3))<<4);
  }

  __syncthreads();
  for (int icb=0; icb<4; ++icb){
    if (icb) __syncthreads();
    for (int s = tid; s < 1360; s += 256){
      int p = s>>2, sub = s&3;
      int yy = (int)(((u32)p*241u)>>13);
      int xi = p - yy*34;
      int gy = gy0 - 1 + yy, gx = gx0 - 1 + xi;
      int c = sub ^ ((xi>>1)&3);
      uint4 o4 = make_uint4(0,0,0,0);
      if ((unsigned)gy < 160u && (unsigned)gx < 160u){
        int cb = icb*32 + c*8;
        uint4 q = *(const uint4*)(c1raw + ((size_t)(gy*WD+gx)*128 + cb));
        u32 ww[4] = {q.x,q.y,q.z,q.w};
        u32 ro[4];
#pragma unroll
        for (int j=0;j<4;++j){
          float lo = bf2f((u16)(ww[j]&0xFFFFu)), hi = bf2f((u16)(ww[j]>>16));
          lo = fmaxf(0.f, lo*scbi[cb+2*j][0]   + scbi[cb+2*j][1]);
          hi = fmaxf(0.f, hi*scbi[cb+2*j+1][0] + scbi[cb+2*j+1][1]);
          ro[j] = pack2(lo, hi);
        }
        o4 = make_uint4(ro[0],ro[1],ro[2],ro[3]);
      }
      *(uint4*)(Xs + p*64 + sub*16) = o4;
    }
    __syncthreads();
#pragma unroll
    for (int tap=0; tap<9; ++tap){
      const int dy = tap/3, dx = tap - dy*3;
      bf16x8 a[4], bw[4];
#pragma unroll
      for (int o=0;o<4;++o)
        bw[o] = *(const bf16x8*)(wp2 + ((size_t)((icb*9 + tap)*4 + kc)*64 + o*16 + l15)*8);
#pragma unroll
      for (int t=0;t<4;++t)
        a[t] = *(const bf16x8*)(Xs + (2*w + (t>>1) + dy)*2176 + xon[t&1][dx]);
#pragma unroll
      for (int t=0;t<4;++t)
#pragma unroll
        for (int o=0;o<4;++o)
          acc[t][o] = MF(a[t], bw[o], acc[t][o]);
    }
  }

  float sa[4]={0,0,0,0}, sq[4]={0,0,0,0};
  for (int t=0;t<4;++t){
    int gy = gy0 + 2*w + (t>>1);
    int gxb = gx0 + (t&1)*16 + kc*4;
    for (int o=0;o<4;++o){
      int oc = o*16 + l15;
#pragma unroll
      for (int r=0;r<4;++r){
        float v = acc[t][o][r];
        raw2[(size_t)(gy*WD + gxb + r)*64 + oc] = f2bf(v);
        sa[o]+=v; sq[o]+=v*v;
      }
    }
  }
  int slot = flat & (nslot-1);
  for (int o=0;o<4;++o){
    float s1_=sa[o], s2_=sq[o];
    s1_+=__shfl_xor(s1_,16); s2_+=__shfl_xor(s2_,16);
    s1_+=__shfl_xor(s1_,32); s2_+=__shfl_xor(s2_,32);
    if (lane<16){
      float* p = statsO + ((size_t)slot*128 + o*16 + l15)*4;
      atomicAdd(p,s1_); atomicAdd(p+1,s2_);
    }
  }
}

// ============================================================================
// row-tiled sobel (bigWS, r13-verified): block=(y,b), coalesced gload16 stage.
// ============================================================================
__global__ __launch_bounds__(256,2) void k_sobelrow(
    char* __restrict__ dout, const float* __restrict__ S1,
    const float* __restrict__ g2, const float* __restrict__ be2,
    u16* __restrict__ edge_base, long ebstride,
    const u16* __restrict__ zeros, int nslot)
{
  __shared__ __align__(16) char Xs[65536];
  __shared__ float ascS[64], abiS[64];
  const int tid = threadIdx.x;
  const int y = blockIdx.x, b = blockIdx.y;

  if (tid < 64){
    float sm=0.f, sq=0.f;
    for (int s=0;s<nslot;++s){ const float* p = S1 + ((size_t)s*128 + tid)*4; sm+=p[0]; sq+=p[1]; }
    float m = sm/NPIXF, v = sq/NPIXF - m*m;
    float sc = g2[tid]*rsqrtf(v + BNEPS);
    ascS[tid] = sc; abiS[tid] = be2[tid] - m*sc;
  }

  const u16* raw2 = (const u16*)(dout + (size_t)b*BATB + SLOTB);
#pragma unroll
  for (int it=0; it<16; ++it){
    int s = it*256 + tid;
    int r = (s >= 2624) ? 2 : ((s >= 1312) ? 1 : 0);
    int sl = s - r*1312;
    int p = sl>>3, c8 = sl&7;
    int yy = y - 1 + r, gx = p - 2;
    const u16* src = zeros + ((tid&63)<<3);
    if (s < 3936 && (unsigned)yy < 160u && (unsigned)gx < 160u)
      src = raw2 + ((size_t)(yy*WD + gx)*64 + c8*8);
    gload16(src, Xs + (it*256 + (tid & ~63))*16);
  }
  asm volatile("s_waitcnt vmcnt(0)" ::: "memory");
  __syncthreads();

  u16* edge = edge_base + (size_t)b*ebstride;
#pragma unroll
  for (int i=0; i<5; ++i){
    int s = i*256 + tid;
    int px = s>>3, c8 = s&7;
    const int ch0 = c8*8;
    float av[8] = {0,0,0,0,0,0,0,0};
    auto TAP = [&](int dy, int dx, float wt){
      int yy = y+dy, xx = px+dx;
      if ((unsigned)yy>=160u || (unsigned)xx>=160u) return;
      uint4 q = *(const uint4*)(Xs + (((1+dy)*1312 + (xx+2)*8 + c8)<<4));
      u32 ww[4] = {q.x,q.y,q.z,q.w};
#pragma unroll
      for (int j=0;j<4;++j){
        float lo = bf2f((u16)(ww[j]&0xFFFFu)), hi = bf2f((u16)(ww[j]>>16));
        lo = fmaxf(0.f, lo*ascS[ch0+2*j]   + abiS[ch0+2*j]);
        hi = fmaxf(0.f, hi*ascS[ch0+2*j+1] + abiS[ch0+2*j+1]);
        av[2*j]   += wt*lo;
        av[2*j+1] += wt*hi;
      }
    };
    TAP(-1,-1,4.f); TAP(-1,0,4.f);
    TAP(0,-2,-2.f); TAP(0,-1,-8.f); TAP(0,1,8.f); TAP(0,2,2.f);
    TAP(1,0,-4.f);  TAP(1,1,-4.f);
    uint4 o;
    o.x = pack2(av[0],av[1]); o.y = pack2(av[2],av[3]);
    o.z = pack2(av[4],av[5]); o.w = pack2(av[6],av[7]);
    *(uint4*)(edge + ((size_t)(y*WD + px)*64 + c8*8)) = o;
  }
}

// ============================================================================
// sobel (standalone, smallWS fallback — verified): raw2(odd-lo) -> edge
// ============================================================================
__global__ __launch_bounds__(256) void k_sobel(
    char* __restrict__ dout, const float* __restrict__ S1,
    const float* __restrict__ g2, const float* __restrict__ be2,
    u16* __restrict__ edge_base, long ebstride, int nslot)
{
  __shared__ float ascS[8], abiS[8];
  int tid = threadIdx.x;
  int b = blockIdx.z, cb = blockIdx.y;
  if (tid < 64){
    int c = cb*8 + (tid&7);
    float sm=0.f, sq=0.f;
    for (int s = tid>>3; s < nslot; s += 8){
      const float* p = S1 + ((size_t)s*128 + c)*4;
      sm += p[0]; sq += p[1];
    }
    sm += __shfl_xor(sm, 8);  sq += __shfl_xor(sq, 8);
    sm += __shfl_xor(sm, 16); sq += __shfl_xor(sq, 16);
    sm += __shfl_xor(sm, 32); sq += __shfl_xor(sq, 32);
    if (tid < 8){
      float m = sm/NPIXF, v = sq/NPIXF - m*m;
      float sc = g2[c]*rsqrtf(v+BNEPS);
      ascS[tid] = sc; abiS[tid] = be2[c] - m*sc;
    }
  }
  __syncthreads();
  int px = blockIdx.x*256 + tid;
  int y = (int)(((u32)px*52429u)>>23);
  int x = px - y*WD;
  const u16* raw2 = (const u16*)(dout + (size_t)b*BATB + SLOTB);
  u16* edge = edge_base + (size_t)b*ebstride;
  float av[8] = {0,0,0,0,0,0,0,0};
  auto TAP = [&](int dy, int dx, float wt){
    int yy = y+dy, xx = x+dx;
    if ((unsigned)yy>=160u || (unsigned)xx>=160u) return;
    uint4 q = *(const uint4*)(raw2 + ((size_t)(yy*WD+xx)*64 + cb*8));
    u32 ww[4] = {q.x,q.y,q.z,q.w};
#pragma unroll
    for (int j=0;j<4;++j){
      float lo = bf2f((u16)(ww[j]&0xFFFFu)), hi = bf2f((u16)(ww[j]>>16));
      lo = fmaxf(0.f, lo*ascS[2*j]   + abiS[2*j]);
      hi = fmaxf(0.f, hi*ascS[2*j+1] + abiS[2*j+1]);
      av[2*j]   += wt*lo;
      av[2*j+1] += wt*hi;
    }
  };
  TAP(-1,-1,4.f); TAP(-1,0,4.f);
  TAP(0,-2,-2.f); TAP(0,-1,-8.f); TAP(0,1,8.f); TAP(0,2,2.f);
  TAP(1,0,-4.f);  TAP(1,1,-4.f);
  uint4 o;
  o.x = pack2(av[0],av[1]); o.y = pack2(av[2],av[3]);
  o.z = pack2(av[4],av[5]); o.w = pack2(av[6],av[7]);
  *(uint4*)(edge + ((size_t)px*64 + cb*8)) = o;
}

// ============================================================================
// conv3/conv4 (132us structure + xb16 staging, r14-verified): 24.6KB per-icb
// phases, lb(256,2). job1: gload16 from xb16 (if avail) else float4-quad.
// job0: edge gload16 + vmcnt(0). mode 2 merged; 0/1 split.
// ============================================================================
__global__ __launch_bounds__(256,2) void k_conv34(
    char* __restrict__ dout, const float* __restrict__ x,
    const u16* __restrict__ xb16,
    const u16* __restrict__ wp3, const u16* __restrict__ wp4,
    float* __restrict__ st3, float* __restrict__ st4,
    const u16* __restrict__ zeros, const u16* __restrict__ edge_base,
    long ebstride, int nslot, int mode)
{
  __shared__ __align__(16) char Xs[24576];
  const int tid = threadIdx.x, lane = tid&63, w = tid>>6;
  const int l15 = lane&15, kc = lane>>4;
  int b, job;
  if (mode == 2){ b = blockIdx.z>>1; job = blockIdx.z&1; }
  else          { b = blockIdx.z;    job = mode; }
  const int gx0 = blockIdx.x*32, gy0 = blockIdx.y*8;
  const u16* wp = job ? wp4 : wp3;
  float* statsO = job ? st4 : st3;
  float* out = job ? (float*)(dout + (size_t)b*BATB)
                   : (float*)(dout + (size_t)b*BATB + SLOTB);
  const float* xb = x + (size_t)b*64*HW;
  const u16* edge = edge_base + (size_t)b*ebstride;
  const u16* nsrc = job ? (xb16 ? xb16 + (size_t)b*HW*64 : nullptr) : edge;

  f32x4 acc[4][4];
  for (int m=0;m<4;++m) for (int t=0;t<4;++t) acc[m][t] = (f32x4){0.f,0.f,0.f,0.f};
  int xon[2][3];
  for (int h=0;h<2;++h) for (int dx=0;dx<3;++dx){
    int xi = l15 + h*16 + dx;
    xon[h][dx] = xi*64 + ((kc ^ ((xi>>1)&3))<<4);
  }

  for (int icb=0; icb<2; ++icb){
    if (icb) __syncthreads();
    if (job == 1 && !nsrc){
      for (int s = tid; s < 1600; s += 256){
        int s10 = (int)(((u32)s*6554u)>>16);
        int q = s - s10*10;
        int cp = (int)(((u32)s10*6554u)>>16);
        int yq = s10 - cp*10;
        int gy = gy0 - 1 + yq;
        int gxq = gx0 - 4 + q*4;
        float fa[4] = {0,0,0,0}, fb[4] = {0,0,0,0};
        if ((unsigned)gy < 160u){
          const float* pa = xb + (size_t)(icb*32 + cp*2)*HW + gy*WD + gxq;
          if (gxq >= 0 && gxq + 3 < 160){
            float4 va = *(const float4*)pa;
            float4 vb = *(const float4*)(pa + HW);
            fa[0]=va.x; fa[1]=va.y; fa[2]=va.z; fa[3]=va.w;
            fb[0]=vb.x; fb[1]=vb.y; fb[2]=vb.z; fb[3]=vb.w;
          } else {
#pragma unroll
            for (int e=0;e<4;++e){
              int gx = gxq + e;
              if ((unsigned)gx < 160u){ fa[e] = pa[e]; fb[e] = pa[e + HW]; }
            }
          }
        }
#pragma unroll
        for (int e=0;e<4;++e){
          int xi = gxq + e - (gx0 - 1);
          if ((unsigned)xi < 34u){
            int phys = (yq*34 + xi)*64 + (((cp>>2) ^ ((xi>>1)&3))<<4) + (cp&3)*4;
            *(u32*)(Xs + phys) = pack2(fa[e], fb[e]);
          }
        }
      }
    } else {
      for (int it=0; it<6; ++it){
        int s = it*256 + tid;
        int p = s>>2, sub = s&3;
        int yy = (int)(((u32)p*241u)>>13);
        int xi = p - yy*34;
        int gy = gy0-1+yy, gx = gx0-1+xi;
        int c = sub ^ ((xi>>1)&3);
        const u16* src = zeros + ((tid&63)<<3);
        if (p<340 && (unsigned)gy<160u && (unsigned)gx<160u)
          src = nsrc + ((size_t)(gy*WD+gx)*64 + icb*32 + c*8);
        gload16(src, Xs + (it*256 + (tid & ~63))*16);
      }
      asm volatile("s_waitcnt vmcnt(0)" ::: "memory");
    }
    __syncthreads();

#pragma unroll
    for (int tap=0; tap<9; ++tap){
      const int dy = tap/3, dx = tap - dy*3;
      bf16x8 a[4], bv[4];
#pragma unroll
      for (int m=0;m<4;++m)
        a[m] = *(const bf16x8*)(wp + ((size_t)((icb*9+tap)*64 + m*16 + l15)*32 + kc*8));
#pragma unroll
      for (int t=0;t<4;++t)
        bv[t] = *(const bf16x8*)(Xs + (2*w + (t>>1) + dy)*2176 + xon[t&1][dx]);
#pragma unroll
      for (int m=0;m<4;++m)
#pragma unroll
        for (int t=0;t<4;++t)
          acc[m][t] = MF(a[m], bv[t], acc[m][t]);
    }
  }

  float sa[4][4], sq[4][4];
  for (int m=0;m<4;++m) for (int r=0;r<4;++r){ sa[m][r]=0.f; sq[m][r]=0.f; }
  for (int m=0;m<4;++m){
    for (int t=0;t<4;++t){
      int gy = gy0 + 2*w + (t>>1);
      int gx = gx0 + (t&1)*16 + l15;
#pragma unroll
      for (int r=0;r<4;++r){
        float v = acc[m][t][r];
        out[(size_t)(m*16 + kc*4 + r)*HW + gy*WD + gx] = v;
        sa[m][r]+=v; sq[m][r]+=v*v;
      }
    }
  }
  int slot = (blockIdx.x + 5*(blockIdx.y + 20*blockIdx.z)) & (nslot-1);
  for (int m=0;m<4;++m)
    for (int r=0;r<4;++r){
      float s1_=sa[m][r], s2_=sq[m][r];
      s1_+=__shfl_xor(s1_,1); s2_+=__shfl_xor(s2_,1);
      s1_+=__shfl_xor(s1_,2); s2_+=__shfl_xor(s2_,2);
      s1_+=__shfl_xor(s1_,4); s2_+=__shfl_xor(s2_,4);
      s1_+=__shfl_xor(s1_,8); s2_+=__shfl_xor(s2_,8);
      if (l15==0){
        float* p = statsO + ((size_t)slot*128 + m*16 + kc*4 + r)*4;
        atomicAdd(p,s1_); atomicAdd(p+1,s2_);
      }
    }
}

// final in-place BN+ReLU on d_out NCHW f32.
__global__ __launch_bounds__(256) void k_bnrelu(
    float* __restrict__ io, const float* __restrict__ f23,
    const float* __restrict__ g3, const float* __restrict__ be3,
    const float* __restrict__ g4, const float* __restrict__ be4)
{
  size_t e = ((size_t)blockIdx.x*256 + threadIdx.x)*8;
  int cg = (int)((e/HW) & 127);
  float* p = io + (size_t)blockIdx.y*3276800 + e;
  float sm,sq,gg,bb;
  if (cg>=64){ int c=cg-64; sm=f23[c*2]; sq=f23[c*2+1]; gg=g3[c]; bb=be3[c]; }
  else       { sm=f23[(128+cg)*2]; sq=f23[(128+cg)*2+1]; gg=g4[cg]; bb=be4[cg]; }
  float m = sm/NPIXF;
  float v = sq/NPIXF - m*m;
  float sc = gg*rsqrtf(v + BNEPS);
  float bi = bb - m*sc;
  float4 a = *(float4*)p;
  float4 bq = *(float4*)(p+4);
  a.x=fmaxf(0.f,a.x*sc+bi); a.y=fmaxf(0.f,a.y*sc+bi);
  a.z=fmaxf(0.f,a.z*sc+bi); a.w=fmaxf(0.f,a.w*sc+bi);
  bq.x=fmaxf(0.f,bq.x*sc+bi); bq.y=fmaxf(0.f,bq.y*sc+bi);
  bq.z=fmaxf(0.f,bq.z*sc+bi); bq.w=fmaxf(0.f,bq.w*sc+bi);
  *(float4*)p = a;
  *(float4*)(p+4) = bq;
}

extern "C" void kernel_launch(void* const* d_in, const int* in_sizes, int n_in,
                              void* d_out, int out_size, void* d_ws, size_t ws_size,
                              hipStream_t stream)
{
  const float* x   = (const float*)d_in[0];
  const float* w1  = (const float*)d_in[1];
  const float* g1  = (const float*)d_in[3];
  const float* be1 = (const float*)d_in[4];
  const float* w2  = (const float*)d_in[5];
  const float* g2  = (const float*)d_in[7];
  const float* be2 = (const float*)d_in[8];
  const float* w3  = (const float*)d_in[9];
  const float* g3  = (const float*)d_in[11];
  const float* be3 = (const float*)d_in[12];
  const float* w4  = (const float*)d_in[13];
  const float* g4  = (const float*)d_in[15];
  const float* be4 = (const float*)d_in[16];
  (void)in_sizes; (void)n_in; (void)out_size;
  // biases b1..b4 dropped — training-mode BN is shift-invariant.

  int nslot = 32;
  auto need = [&](int ns)->size_t{
    return (size_t)4*ns*128*4*4 + 4096 + (size_t)(8192+73728+36864+36864)*2 + 1024;
  };
  while (nslot > 1 && need(nslot) > ws_size) nslot >>= 1;
  if (need(nslot) > ws_size) return;

  char* ws = (char*)d_ws;
  float* S = (float*)ws;
  size_t stg = (size_t)nslot*128*4;
  float* S0=S, *S1=S+stg, *S2=S+2*stg, *S3=S+3*stg;
  float* F = S + 4*stg;
  u16* wp1 = (u16*)(F + 1024);
  u16* wp2 = wp1 + 8192;
  u16* wp3 = wp2 + 73728;
  u16* wp4 = wp3 + 36864;
  u16* zeros = wp4 + 36864;
  size_t base = need(nslot);
  bool bigB = (ws_size >= base + 26214400ull);          // edge in ws
  bool bigA = (ws_size >= base + 2*26214400ull);        // + xb16 in ws
  u16* edge_base; long ebstride;
  if (bigB){ edge_base = (u16*)(ws + base); ebstride = 64L*HW; }
  else     { edge_base = (u16*)((char*)d_out + 3276800); ebstride = BATB/2; }
  u16* xb16 = bigA ? (u16*)(ws + base + 26214400) : nullptr;

  hipMemsetAsync(S, 0, 4*stg*sizeof(float), stream);
  hipMemsetAsync(zeros, 0, 1024, stream);

  k_prepw<<<464, 256, 0, stream>>>(w1, w2, w3, w4, wp1, wp2, wp3, wp4);
  k_conv1<<<dim3(200,8), 256, 0, stream>>>(x, wp1, (char*)d_out, S0, nslot, xb16);
  k_conv2<<<dim3(5,20,8), 256, 0, stream>>>((char*)d_out, wp2, S0, g1, be1, S1, nslot);
  if (bigB){
    k_sobelrow<<<dim3(160,8), 256, 0, stream>>>((char*)d_out, S1, g2, be2,
                                                edge_base, ebstride, zeros, nslot);
    k_conv34<<<dim3(5,20,16), 256, 0, stream>>>((char*)d_out, x, xb16, wp3, wp4, S2, S3,
                                                zeros, edge_base, ebstride, nslot, 2);
  } else {
    k_sobel<<<dim3(100,8,8), 256, 0, stream>>>((char*)d_out, S1, g2, be2,
                                               edge_base, ebstride, nslot);
    k_conv34<<<dim3(5,20,8), 256, 0, stream>>>((char*)d_out, x, nullptr, wp3, wp4, S2, S3,
                                               zeros, edge_base, ebstride, nslot, 0);
    k_conv34<<<dim3(5,20,8), 256, 0, stream>>>((char*)d_out, x, nullptr, wp3, wp4, S2, S3,
                                               zeros, edge_base, ebstride, nslot, 1);
  }
  k_fold23<<<1, 256, 0, stream>>>(S2, S3, F, nslot);
  k_bnrelu<<<dim3(1600,8), 256, 0, stream>>>((float*)d_out, F, g3, be3, g4, be4);
}

// Round 17
// 320.834 us; speedup vs baseline: 1.0328x; 1.0015x over previous
//
#include <hip/hip_runtime.h>

typedef unsigned short u16;
typedef unsigned int u32;
typedef __attribute__((ext_vector_type(8))) short bf16x8;
typedef __attribute__((ext_vector_type(4))) float f32x4;
typedef __attribute__((ext_vector_type(4))) unsigned int u32x4;

#define WD 160
#define HW 25600
#define NPIXF 204800.0f
#define BNEPS 1e-5f
#define SLOTB 6553600ll
#define BATB  13107200ll

__device__ __forceinline__ float bf2f(u16 u){ return __uint_as_float(((u32)u)<<16); }
__device__ __forceinline__ u16 f2bf(float f){ u32 x=__float_as_uint(f); return (u16)((x + 0x7FFFu + ((x>>16)&1u))>>16); }
__device__ __forceinline__ u32 pack2(float a,float b){ return (u32)f2bf(a) | ((u32)f2bf(b)<<16); }

__device__ __forceinline__ f32x4 MF(bf16x8 a, bf16x8 b, f32x4 c){
  return __builtin_amdgcn_mfma_f32_16x16x32_bf16(a, b, c, 0, 0, 0);
}
__device__ __forceinline__ void gload16(const void* g, void* l){
  __builtin_amdgcn_global_load_lds((const __attribute__((address_space(1))) void*)(g),
                                   (__attribute__((address_space(3))) void*)(l), 16, 0, 0);
}

// ============================================================================
// weight prep: wp1 [icb2][kc4][oc128][i8]  wp2 [icb4][tap9][kc4][oc64][i8]
// wp3/wp4 [icb2][tap9][oc64][k32]
// ============================================================================
__global__ __launch_bounds__(256) void k_prepw(
    const float* __restrict__ w1, const float* __restrict__ w2,
    const float* __restrict__ w3, const float* __restrict__ w4,
    u16* __restrict__ wp1, u16* __restrict__ wp2,
    u16* __restrict__ wp3, u16* __restrict__ wp4)
{
  int t = blockIdx.x*256 + threadIdx.x;
  if (t < 8192){
    int i = t&7, oc = (t>>3)&127, kc = (t>>10)&3, icb = t>>12;
    wp1[t] = f2bf(w1[oc*64 + icb*32 + kc*8 + i]);
  }
  int u = t - 8192;
  if (u >= 0 && u < 73728){
    int i = u&7, oc = (u>>3)&63, kc = (u>>9)&3, v = u>>11;
    int icb = (v*57)>>9; int tap = v - icb*9;
    wp2[u] = f2bf(w2[(oc*128 + icb*32 + kc*8 + i)*9 + tap]);
  }
  int u3 = t - (8192+73728);
  if (u3 >= 0 && u3 < 36864){
    int k = u3&31, oc = (u3>>5)&63, v = u3>>11;
    int icb = (v >= 9) ? 1 : 0; int tap = v - icb*9;
    wp3[u3] = f2bf(w3[(oc*64 + icb*32 + k)*9 + tap]);
    wp4[u3] = f2bf(w4[(oc*64 + icb*32 + k)*9 + tap]);
  }
}

// ============================================================================
// conv1 (verified): b128 conflict-free LDS staging from x f32.
// xb16 mirror COALESCED from LDS post-sync, nontemporal stores.
// ============================================================================
__global__ __launch_bounds__(256,4) void k_conv1(
    const float* __restrict__ x, const u16* __restrict__ wp1,
    char* __restrict__ dout, float* __restrict__ stats, int nslot,
    u16* __restrict__ xb16o)
{
  __shared__ __align__(16) char Xs[16384];
  const int tid = threadIdx.x, lane = tid&63, w = tid>>6;
  const int l15 = lane&15, kc = lane>>4;
  int flat = blockIdx.x + 200*blockIdx.y;
  flat = (flat&7)*200 + (flat>>3);
  const int b = flat/200, bx = flat - b*200;
  const int px0 = bx*128;
  const float* xb = x + (size_t)b*64*HW;

#pragma unroll
  for (int q=0; q<4; ++q){
    int s = q*256 + tid;
    int px = s & 127, ck = (s>>7)&3, icb = s>>9;
    const float* pb = xb + (size_t)(icb*32 + ck*8)*HW + px0 + px;
    u32 w4[4];
#pragma unroll
    for (int j=0;j<4;++j)
      w4[j] = pack2(pb[(size_t)(2*j)*HW], pb[(size_t)(2*j+1)*HW]);
    *(uint4*)(Xs + icb*8192 + px*64 + ((ck ^ ((px>>1)&3))<<4))
        = make_uint4(w4[0],w4[1],w4[2],w4[3]);
  }
  __syncthreads();

  if (xb16o){
    u16* ob = xb16o + (size_t)b*HW*64 + (size_t)px0*64;
#pragma unroll
    for (int q=0; q<4; ++q){
      int s = q*256 + tid;               // out chunk s -> consecutive 16B
      int px = s>>3, c = s&7;
      int icb = c>>2, ck = c&3;
      u32x4 v = *(const u32x4*)(Xs + icb*8192 + px*64 + ((ck ^ ((px>>1)&3))<<4));
      __builtin_nontemporal_store(v, (u32x4*)(ob + (size_t)s*8));
    }
  }

  f32x4 acc[4][4];
  for (int t=0;t<4;++t) for (int o=0;o<4;++o) acc[t][o] = (f32x4){0.f,0.f,0.f,0.f};
  const int och = (w>>1)*64;
  int a1off[4];
  for (int t=0;t<4;++t){
    int px = (w&1)*64 + t*16 + l15;
    a1off[t] = px*64 + ((kc ^ ((px>>1)&3))<<4);
  }
#pragma unroll
  for (int icb=0; icb<2; ++icb){
    bf16x8 a[4], bw[4];
#pragma unroll
    for (int t=0;t<4;++t) a[t] = *(const bf16x8*)(Xs + icb*8192 + a1off[t]);
#pragma unroll
    for (int o=0;o<4;++o)
      bw[o] = *(const bf16x8*)(wp1 + ((size_t)(icb*4 + kc)*128 + och + o*16 + l15)*8);
#pragma unroll
    for (int t=0;t<4;++t)
#pragma unroll
      for (int o=0;o<4;++o)
        acc[t][o] = MF(a[t], bw[o], acc[t][o]);
  }

  u16* c1 = (u16*)(dout + (size_t)b*BATB);
  float sa[4]={0,0,0,0}, sq[4]={0,0,0,0};
  for (int t=0;t<4;++t){
    int pxb = px0 + (w&1)*64 + t*16 + kc*4;
    for (int o=0;o<4;++o){
      int oc = och + o*16 + l15;
#pragma unroll
      for (int r=0;r<4;++r){
        float v = acc[t][o][r];
        c1[(size_t)(pxb + r)*128 + oc] = f2bf(v);
        sa[o]+=v; sq[o]+=v*v;
      }
    }
  }
  const int slot = flat & (nslot-1);
  for (int o=0;o<4;++o){
    float s1_=sa[o], s2_=sq[o];
    s1_+=__shfl_xor(s1_,16); s2_+=__shfl_xor(s2_,16);
    s1_+=__shfl_xor(s1_,32); s2_+=__shfl_xor(s2_,32);
    if (lane < 16){
      float* p = stats + ((size_t)slot*128 + och + o*16 + l15)*4;
      atomicAdd(p, s1_); atomicAdd(p+1, s2_);
    }
  }
}

// fold S2 (t<128) and S3 (t>=128) -> f23[256][2]
__global__ void k_fold23(const float* __restrict__ s2, const float* __restrict__ s3,
                         float* __restrict__ f23, int nslot){
  int t = threadIdx.x;
  const float* src = (t < 128) ? s2 : s3;
  int c = t & 127;
  float sm=0.f, sq=0.f;
  for (int s=0;s<nslot;++s){ const float* p = src + ((size_t)s*128 + c)*4; sm+=p[0]; sq+=p[1]; }
  f23[t*2] = sm; f23[t*2+1] = sq;
}

// ============================================================================
// conv2 (verified): BN1 affine+relu in register staging. raw2 -> odd-lo.
// ============================================================================
__global__ __launch_bounds__(256,4) void k_conv2(
    char* __restrict__ dout, const u16* __restrict__ wp2,
    const float* __restrict__ S0, const float* __restrict__ g1,
    const float* __restrict__ be1,
    float* __restrict__ statsO, int nslot)
{
  __shared__ __align__(16) char Xs[21760];
  __shared__ __align__(16) float scbi[128][2];
  const int tid = threadIdx.x, lane = tid&63, w = tid>>6;
  const int l15 = lane&15, kc = lane>>4;
  int flat = blockIdx.x + 5*(blockIdx.y + 20*blockIdx.z);
  flat = (flat&7)*100 + (flat>>3);
  const int b = flat/100; int r100 = flat - b*100;
  const int by = r100/5, bx = r100 - by*5;
  const int gx0 = bx*32, gy0 = by*8;
  const u16* c1raw = (const u16*)(dout + (size_t)b*BATB);
  u16* raw2 = (u16*)(dout + (size_t)b*BATB + SLOTB);

  if (tid < 128){
    float sm=0.f, sq=0.f;
    for (int s=0;s<nslot;++s){ const float* p = S0 + ((size_t)s*128 + tid)*4; sm+=p[0]; sq+=p[1]; }
    float m = sm/NPIXF;
    float v = sq/NPIXF - m*m;
    float sc = g1[tid]*rsqrtf(v + BNEPS);
    scbi[tid][0] = sc; scbi[tid][1] = be1[tid] - m*sc;
  }

  f32x4 acc[4][4];
  for (int t=0;t<4;++t) for (int o=0;o<4;++o) acc[t][o] = (f32x4){0.f,0.f,0.f,0.f};

  int xon[2][3];
  for (int h=0;h<2;++h) for (int dx=0;dx<3;++dx){
    int xi = l15 + h*16 + dx;
    xon[h][dx] = xi*64 + ((kc ^ ((xi>>1)&3))<<4);
  }

  __syncthreads();
  for (int icb=0; icb<4; ++icb){
    if (icb) __syncthreads();
    for (int s = tid; s < 1360; s += 256){
      int p = s>>2, sub = s&3;
      int yy = (int)(((u32)p*241u)>>13);
      int xi = p - yy*34;
      int gy = gy0 - 1 + yy, gx = gx0 - 1 + xi;
      int c = sub ^ ((xi>>1)&3);
      uint4 o4 = make_uint4(0,0,0,0);
      if ((unsigned)gy < 160u && (unsigned)gx < 160u){
        int cb = icb*32 + c*8;
        uint4 q = *(const uint4*)(c1raw + ((size_t)(gy*WD+gx)*128 + cb));
        u32 ww[4] = {q.x,q.y,q.z,q.w};
        u32 ro[4];
#pragma unroll
        for (int j=0;j<4;++j){
          float lo = bf2f((u16)(ww[j]&0xFFFFu)), hi = bf2f((u16)(ww[j]>>16));
          lo = fmaxf(0.f, lo*scbi[cb+2*j][0]   + scbi[cb+2*j][1]);
          hi = fmaxf(0.f, hi*scbi[cb+2*j+1][0] + scbi[cb+2*j+1][1]);
          ro[j] = pack2(lo, hi);
        }
        o4 = make_uint4(ro[0],ro[1],ro[2],ro[3]);
      }
      *(uint4*)(Xs + p*64 + sub*16) = o4;
    }
    __syncthreads();
#pragma unroll
    for (int tap=0; tap<9; ++tap){
      const int dy = tap/3, dx = tap - dy*3;
      bf16x8 a[4], bw[4];
#pragma unroll
      for (int o=0;o<4;++o)
        bw[o] = *(const bf16x8*)(wp2 + ((size_t)((icb*9 + tap)*4 + kc)*64 + o*16 + l15)*8);
#pragma unroll
      for (int t=0;t<4;++t)
        a[t] = *(const bf16x8*)(Xs + (2*w + (t>>1) + dy)*2176 + xon[t&1][dx]);
#pragma unroll
      for (int t=0;t<4;++t)
#pragma unroll
        for (int o=0;o<4;++o)
          acc[t][o] = MF(a[t], bw[o], acc[t][o]);
    }
  }

  float sa[4]={0,0,0,0}, sq[4]={0,0,0,0};
  for (int t=0;t<4;++t){
    int gy = gy0 + 2*w + (t>>1);
    int gxb = gx0 + (t&1)*16 + kc*4;
    for (int o=0;o<4;++o){
      int oc = o*16 + l15;
#pragma unroll
      for (int r=0;r<4;++r){
        float v = acc[t][o][r];
        raw2[(size_t)(gy*WD + gxb + r)*64 + oc] = f2bf(v);
        sa[o]+=v; sq[o]+=v*v;
      }
    }
  }
  int slot = flat & (nslot-1);
  for (int o=0;o<4;++o){
    float s1_=sa[o], s2_=sq[o];
    s1_+=__shfl_xor(s1_,16); s2_+=__shfl_xor(s2_,16);
    s1_+=__shfl_xor(s1_,32); s2_+=__shfl_xor(s2_,32);
    if (lane<16){
      float* p = statsO + ((size_t)slot*128 + o*16 + l15)*4;
      atomicAdd(p,s1_); atomicAdd(p+1,s2_);
    }
  }
}

// ============================================================================
// row-tiled sobel (bigWS, r13-verified): block=(y,b), coalesced gload16 stage.
// ============================================================================
__global__ __launch_bounds__(256,2) void k_sobelrow(
    char* __restrict__ dout, const float* __restrict__ S1,
    const float* __restrict__ g2, const float* __restrict__ be2,
    u16* __restrict__ edge_base, long ebstride,
    const u16* __restrict__ zeros, int nslot)
{
  __shared__ __align__(16) char Xs[65536];
  __shared__ float ascS[64], abiS[64];
  const int tid = threadIdx.x;
  const int y = blockIdx.x, b = blockIdx.y;

  if (tid < 64){
    float sm=0.f, sq=0.f;
    for (int s=0;s<nslot;++s){ const float* p = S1 + ((size_t)s*128 + tid)*4; sm+=p[0]; sq+=p[1]; }
    float m = sm/NPIXF, v = sq/NPIXF - m*m;
    float sc = g2[tid]*rsqrtf(v + BNEPS);
    ascS[tid] = sc; abiS[tid] = be2[tid] - m*sc;
  }

  const u16* raw2 = (const u16*)(dout + (size_t)b*BATB + SLOTB);
#pragma unroll
  for (int it=0; it<16; ++it){
    int s = it*256 + tid;
    int r = (s >= 2624) ? 2 : ((s >= 1312) ? 1 : 0);
    int sl = s - r*1312;
    int p = sl>>3, c8 = sl&7;
    int yy = y - 1 + r, gx = p - 2;
    const u16* src = zeros + ((tid&63)<<3);
    if (s < 3936 && (unsigned)yy < 160u && (unsigned)gx < 160u)
      src = raw2 + ((size_t)(yy*WD + gx)*64 + c8*8);
    gload16(src, Xs + (it*256 + (tid & ~63))*16);
  }
  asm volatile("s_waitcnt vmcnt(0)" ::: "memory");
  __syncthreads();

  u16* edge = edge_base + (size_t)b*ebstride;
#pragma unroll
  for (int i=0; i<5; ++i){
    int s = i*256 + tid;
    int px = s>>3, c8 = s&7;
    const int ch0 = c8*8;
    float av[8] = {0,0,0,0,0,0,0,0};
    auto TAP = [&](int dy, int dx, float wt){
      int yy = y+dy, xx = px+dx;
      if ((unsigned)yy>=160u || (unsigned)xx>=160u) return;
      uint4 q = *(const uint4*)(Xs + (((1+dy)*1312 + (xx+2)*8 + c8)<<4));
      u32 ww[4] = {q.x,q.y,q.z,q.w};
#pragma unroll
      for (int j=0;j<4;++j){
        float lo = bf2f((u16)(ww[j]&0xFFFFu)), hi = bf2f((u16)(ww[j]>>16));
        lo = fmaxf(0.f, lo*ascS[ch0+2*j]   + abiS[ch0+2*j]);
        hi = fmaxf(0.f, hi*ascS[ch0+2*j+1] + abiS[ch0+2*j+1]);
        av[2*j]   += wt*lo;
        av[2*j+1] += wt*hi;
      }
    };
    TAP(-1,-1,4.f); TAP(-1,0,4.f);
    TAP(0,-2,-2.f); TAP(0,-1,-8.f); TAP(0,1,8.f); TAP(0,2,2.f);
    TAP(1,0,-4.f);  TAP(1,1,-4.f);
    uint4 o;
    o.x = pack2(av[0],av[1]); o.y = pack2(av[2],av[3]);
    o.z = pack2(av[4],av[5]); o.w = pack2(av[6],av[7]);
    *(uint4*)(edge + ((size_t)(y*WD + px)*64 + c8*8)) = o;
  }
}

// ============================================================================
// sobel (standalone, smallWS fallback — verified): raw2(odd-lo) -> edge
// ============================================================================
__global__ __launch_bounds__(256) void k_sobel(
    char* __restrict__ dout, const float* __restrict__ S1,
    const float* __restrict__ g2, const float* __restrict__ be2,
    u16* __restrict__ edge_base, long ebstride, int nslot)
{
  __shared__ float ascS[8], abiS[8];
  int tid = threadIdx.x;
  int b = blockIdx.z, cb = blockIdx.y;
  if (tid < 64){
    int c = cb*8 + (tid&7);
    float sm=0.f, sq=0.f;
    for (int s = tid>>3; s < nslot; s += 8){
      const float* p = S1 + ((size_t)s*128 + c)*4;
      sm += p[0]; sq += p[1];
    }
    sm += __shfl_xor(sm, 8);  sq += __shfl_xor(sq, 8);
    sm += __shfl_xor(sm, 16); sq += __shfl_xor(sq, 16);
    sm += __shfl_xor(sm, 32); sq += __shfl_xor(sq, 32);
    if (tid < 8){
      float m = sm/NPIXF, v = sq/NPIXF - m*m;
      float sc = g2[c]*rsqrtf(v+BNEPS);
      ascS[tid] = sc; abiS[tid] = be2[c] - m*sc;
    }
  }
  __syncthreads();
  int px = blockIdx.x*256 + tid;
  int y = (int)(((u32)px*52429u)>>23);
  int x = px - y*WD;
  const u16* raw2 = (const u16*)(dout + (size_t)b*BATB + SLOTB);
  u16* edge = edge_base + (size_t)b*ebstride;
  float av[8] = {0,0,0,0,0,0,0,0};
  auto TAP = [&](int dy, int dx, float wt){
    int yy = y+dy, xx = x+dx;
    if ((unsigned)yy>=160u || (unsigned)xx>=160u) return;
    uint4 q = *(const uint4*)(raw2 + ((size_t)(yy*WD+xx)*64 + cb*8));
    u32 ww[4] = {q.x,q.y,q.z,q.w};
#pragma unroll
    for (int j=0;j<4;++j){
      float lo = bf2f((u16)(ww[j]&0xFFFFu)), hi = bf2f((u16)(ww[j]>>16));
      lo = fmaxf(0.f, lo*ascS[2*j]   + abiS[2*j]);
      hi = fmaxf(0.f, hi*ascS[2*j+1] + abiS[2*j+1]);
      av[2*j]   += wt*lo;
      av[2*j+1] += wt*hi;
    }
  };
  TAP(-1,-1,4.f); TAP(-1,0,4.f);
  TAP(0,-2,-2.f); TAP(0,-1,-8.f); TAP(0,1,8.f); TAP(0,2,2.f);
  TAP(1,0,-4.f);  TAP(1,1,-4.f);
  uint4 o;
  o.x = pack2(av[0],av[1]); o.y = pack2(av[2],av[3]);
  o.z = pack2(av[4],av[5]); o.w = pack2(av[6],av[7]);
  *(uint4*)(edge + ((size_t)px*64 + cb*8)) = o;
}

// ============================================================================
// conv3/conv4 — r16 structure, occupancy bump lb(256,2) -> lb(256,3):
// 24.6KB per-icb phases; job1 gload16 from xb16 (if avail) else float4-quad;
// job0 edge gload16 + vmcnt(0). mode 2 merged; 0/1 split.
// ============================================================================
__global__ __launch_bounds__(256,3) void k_conv34(
    char* __restrict__ dout, const float* __restrict__ x,
    const u16* __restrict__ xb16,
    const u16* __restrict__ wp3, const u16* __restrict__ wp4,
    float* __restrict__ st3, float* __restrict__ st4,
    const u16* __restrict__ zeros, const u16* __restrict__ edge_base,
    long ebstride, int nslot, int mode)
{
  __shared__ __align__(16) char Xs[24576];
  const int tid = threadIdx.x, lane = tid&63, w = tid>>6;
  const int l15 = lane&15, kc = lane>>4;
  int b, job;
  if (mode == 2){ b = blockIdx.z>>1; job = blockIdx.z&1; }
  else          { b = blockIdx.z;    job = mode; }
  const int gx0 = blockIdx.x*32, gy0 = blockIdx.y*8;
  const u16* wp = job ? wp4 : wp3;
  float* statsO = job ? st4 : st3;
  float* out = job ? (float*)(dout + (size_t)b*BATB)
                   : (float*)(dout + (size_t)b*BATB + SLOTB);
  const float* xb = x + (size_t)b*64*HW;
  const u16* edge = edge_base + (size_t)b*ebstride;
  const u16* nsrc = job ? (xb16 ? xb16 + (size_t)b*HW*64 : nullptr) : edge;

  f32x4 acc[4][4];
  for (int m=0;m<4;++m) for (int t=0;t<4;++t) acc[m][t] = (f32x4){0.f,0.f,0.f,0.f};
  int xon[2][3];
  for (int h=0;h<2;++h) for (int dx=0;dx<3;++dx){
    int xi = l15 + h*16 + dx;
    xon[h][dx] = xi*64 + ((kc ^ ((xi>>1)&3))<<4);
  }

  for (int icb=0; icb<2; ++icb){
    if (icb) __syncthreads();
    if (job == 1 && !nsrc){
      for (int s = tid; s < 1600; s += 256){
        int s10 = (int)(((u32)s*6554u)>>16);
        int q = s - s10*10;
        int cp = (int)(((u32)s10*6554u)>>16);
        int yq = s10 - cp*10;
        int gy = gy0 - 1 + yq;
        int gxq = gx0 - 4 + q*4;
        float fa[4] = {0,0,0,0}, fb[4] = {0,0,0,0};
        if ((unsigned)gy < 160u){
          const float* pa = xb + (size_t)(icb*32 + cp*2)*HW + gy*WD + gxq;
          if (gxq >= 0 && gxq + 3 < 160){
            float4 va = *(const float4*)pa;
            float4 vb = *(const float4*)(pa + HW);
            fa[0]=va.x; fa[1]=va.y; fa[2]=va.z; fa[3]=va.w;
            fb[0]=vb.x; fb[1]=vb.y; fb[2]=vb.z; fb[3]=vb.w;
          } else {
#pragma unroll
            for (int e=0;e<4;++e){
              int gx = gxq + e;
              if ((unsigned)gx < 160u){ fa[e] = pa[e]; fb[e] = pa[e + HW]; }
            }
          }
        }
#pragma unroll
        for (int e=0;e<4;++e){
          int xi = gxq + e - (gx0 - 1);
          if ((unsigned)xi < 34u){
            int phys = (yq*34 + xi)*64 + (((cp>>2) ^ ((xi>>1)&3))<<4) + (cp&3)*4;
            *(u32*)(Xs + phys) = pack2(fa[e], fb[e]);
          }
        }
      }
    } else {
      for (int it=0; it<6; ++it){
        int s = it*256 + tid;
        int p = s>>2, sub = s&3;
        int yy = (int)(((u32)p*241u)>>13);
        int xi = p - yy*34;
        int gy = gy0-1+yy, gx = gx0-1+xi;
        int c = sub ^ ((xi>>1)&3);
        const u16* src = zeros + ((tid&63)<<3);
        if (p<340 && (unsigned)gy<160u && (unsigned)gx<160u)
          src = nsrc + ((size_t)(gy*WD+gx)*64 + icb*32 + c*8);
        gload16(src, Xs + (it*256 + (tid & ~63))*16);
      }
      asm volatile("s_waitcnt vmcnt(0)" ::: "memory");
    }
    __syncthreads();

#pragma unroll
    for (int tap=0; tap<9; ++tap){
      const int dy = tap/3, dx = tap - dy*3;
      bf16x8 a[4], bv[4];
#pragma unroll
      for (int m=0;m<4;++m)
        a[m] = *(const bf16x8*)(wp + ((size_t)((icb*9+tap)*64 + m*16 + l15)*32 + kc*8));
#pragma unroll
      for (int t=0;t<4;++t)
        bv[t] = *(const bf16x8*)(Xs + (2*w + (t>>1) + dy)*2176 + xon[t&1][dx]);
#pragma unroll
      for (int m=0;m<4;++m)
#pragma unroll
        for (int t=0;t<4;++t)
          acc[m][t] = MF(a[m], bv[t], acc[m][t]);
    }
  }

  float sa[4][4], sq[4][4];
  for (int m=0;m<4;++m) for (int r=0;r<4;++r){ sa[m][r]=0.f; sq[m][r]=0.f; }
  for (int m=0;m<4;++m){
    for (int t=0;t<4;++t){
      int gy = gy0 + 2*w + (t>>1);
      int gx = gx0 + (t&1)*16 + l15;
#pragma unroll
      for (int r=0;r<4;++r){
        float v = acc[m][t][r];
        out[(size_t)(m*16 + kc*4 + r)*HW + gy*WD + gx] = v;
        sa[m][r]+=v; sq[m][r]+=v*v;
      }
    }
  }
  int slot = (blockIdx.x + 5*(blockIdx.y + 20*blockIdx.z)) & (nslot-1);
  for (int m=0;m<4;++m)
    for (int r=0;r<4;++r){
      float s1_=sa[m][r], s2_=sq[m][r];
      s1_+=__shfl_xor(s1_,1); s2_+=__shfl_xor(s2_,1);
      s1_+=__shfl_xor(s1_,2); s2_+=__shfl_xor(s2_,2);
      s1_+=__shfl_xor(s1_,4); s2_+=__shfl_xor(s2_,4);
      s1_+=__shfl_xor(s1_,8); s2_+=__shfl_xor(s2_,8);
      if (l15==0){
        float* p = statsO + ((size_t)slot*128 + m*16 + kc*4 + r)*4;
        atomicAdd(p,s1_); atomicAdd(p+1,s2_);
      }
    }
}

// final in-place BN+ReLU on d_out NCHW f32.
__global__ __launch_bounds__(256) void k_bnrelu(
    float* __restrict__ io, const float* __restrict__ f23,
    const float* __restrict__ g3, const float* __restrict__ be3,
    const float* __restrict__ g4, const float* __restrict__ be4)
{
  size_t e = ((size_t)blockIdx.x*256 + threadIdx.x)*8;
  int cg = (int)((e/HW) & 127);
  float* p = io + (size_t)blockIdx.y*3276800 + e;
  float sm,sq,gg,bb;
  if (cg>=64){ int c=cg-64; sm=f23[c*2]; sq=f23[c*2+1]; gg=g3[c]; bb=be3[c]; }
  else       { sm=f23[(128+cg)*2]; sq=f23[(128+cg)*2+1]; gg=g4[cg]; bb=be4[cg]; }
  float m = sm/NPIXF;
  float v = sq/NPIXF - m*m;
  float sc = gg*rsqrtf(v + BNEPS);
  float bi = bb - m*sc;
  float4 a = *(float4*)p;
  float4 bq = *(float4*)(p+4);
  a.x=fmaxf(0.f,a.x*sc+bi); a.y=fmaxf(0.f,a.y*sc+bi);
  a.z=fmaxf(0.f,a.z*sc+bi); a.w=fmaxf(0.f,a.w*sc+bi);
  bq.x=fmaxf(0.f,bq.x*sc+bi); bq.y=fmaxf(0.f,bq.y*sc+bi);
  bq.z=fmaxf(0.f,bq.z*sc+bi); bq.w=fmaxf(0.f,bq.w*sc+bi);
  *(float4*)p = a;
  *(float4*)(p+4) = bq;
}

extern "C" void kernel_launch(void* const* d_in, const int* in_sizes, int n_in,
                              void* d_out, int out_size, void* d_ws, size_t ws_size,
                              hipStream_t stream)
{
  const float* x   = (const float*)d_in[0];
  const float* w1  = (const float*)d_in[1];
  const float* g1  = (const float*)d_in[3];
  const float* be1 = (const float*)d_in[4];
  const float* w2  = (const float*)d_in[5];
  const float* g2  = (const float*)d_in[7];
  const float* be2 = (const float*)d_in[8];
  const float* w3  = (const float*)d_in[9];
  const float* g3  = (const float*)d_in[11];
  const float* be3 = (const float*)d_in[12];
  const float* w4  = (const float*)d_in[13];
  const float* g4  = (const float*)d_in[15];
  const float* be4 = (const float*)d_in[16];
  (void)in_sizes; (void)n_in; (void)out_size;
  // biases b1..b4 dropped — training-mode BN is shift-invariant.

  int nslot = 32;
  auto need = [&](int ns)->size_t{
    return (size_t)4*ns*128*4*4 + 4096 + (size_t)(8192+73728+36864+36864)*2 + 1024;
  };
  while (nslot > 1 && need(nslot) > ws_size) nslot >>= 1;
  if (need(nslot) > ws_size) return;

  char* ws = (char*)d_ws;
  float* S = (float*)ws;
  size_t stg = (size_t)nslot*128*4;
  float* S0=S, *S1=S+stg, *S2=S+2*stg, *S3=S+3*stg;
  float* F = S + 4*stg;
  u16* wp1 = (u16*)(F + 1024);
  u16* wp2 = wp1 + 8192;
  u16* wp3 = wp2 + 73728;
  u16* wp4 = wp3 + 36864;
  u16* zeros = wp4 + 36864;
  size_t base = need(nslot);
  bool bigB = (ws_size >= base + 26214400ull);          // edge in ws
  bool bigA = (ws_size >= base + 2*26214400ull);        // + xb16 in ws
  u16* edge_base; long ebstride;
  if (bigB){ edge_base = (u16*)(ws + base); ebstride = 64L*HW; }
  else     { edge_base = (u16*)((char*)d_out + 3276800); ebstride = BATB/2; }
  u16* xb16 = bigA ? (u16*)(ws + base + 26214400) : nullptr;

  hipMemsetAsync(S, 0, 4*stg*sizeof(float), stream);
  hipMemsetAsync(zeros, 0, 1024, stream);

  k_prepw<<<464, 256, 0, stream>>>(w1, w2, w3, w4, wp1, wp2, wp3, wp4);
  k_conv1<<<dim3(200,8), 256, 0, stream>>>(x, wp1, (char*)d_out, S0, nslot, xb16);
  k_conv2<<<dim3(5,20,8), 256, 0, stream>>>((char*)d_out, wp2, S0, g1, be1, S1, nslot);
  if (bigB){
    k_sobelrow<<<dim3(160,8), 256, 0, stream>>>((char*)d_out, S1, g2, be2,
                                                edge_base, ebstride, zeros, nslot);
    k_conv34<<<dim3(5,20,16), 256, 0, stream>>>((char*)d_out, x, xb16, wp3, wp4, S2, S3,
                                                zeros, edge_base, ebstride, nslot, 2);
  } else {
    k_sobel<<<dim3(100,8,8), 256, 0, stream>>>((char*)d_out, S1, g2, be2,
                                               edge_base, ebstride, nslot);
    k_conv34<<<dim3(5,20,8), 256, 0, stream>>>((char*)d_out, x, nullptr, wp3, wp4, S2, S3,
                                               zeros, edge_base, ebstride, nslot, 0);
    k_conv34<<<dim3(5,20,8), 256, 0, stream>>>((char*)d_out, x, nullptr, wp3, wp4, S2, S3,
                                               zeros, edge_base, ebstride, nslot, 1);
  }
  k_fold23<<<1, 256, 0, stream>>>(S2, S3, F, nslot);
  k_bnrelu<<<dim3(1600,8), 256, 0, stream>>>((float*)d_out, F, g3, be3, g4, be4);
}